// Round 2
// baseline (952.888 us; speedup 1.0000x reference)
//
#include <hip/hip_runtime.h>
#include <cstdint>

// ---------------------------------------------------------------------------
// PureCorrelation: out = (mask' . relu(Q @ Kp^T)) @ Vp
//   Kp = K W1^T + b1,  Vp = V W2^T + b2,  mask' = mask with col0 forced true.
// Fused flash-style (no softmax -> no rescaling): per 32-row Q-tile,
// accumulate O += (mask.relu(Q Kp^T)) Vp over 128-key k-tiles, alpha never
// materialized. Mask pre-packed to bits (268MB -> 8.4MB).
// ---------------------------------------------------------------------------

typedef __bf16 bf16x8 __attribute__((ext_vector_type(8)));
typedef float f32x4 __attribute__((ext_vector_type(4)));

__device__ __forceinline__ unsigned short f2bf(float f) {
  unsigned int u = __float_as_uint(f);
  u += 0x7fffu + ((u >> 16) & 1u);
  return (unsigned short)(u >> 16);
}

// async global->LDS, 16B per lane. LDS dest is wave-uniform base + lane*16.
__device__ __forceinline__ void async_load16(const void* g, void* l) {
  __builtin_amdgcn_global_load_lds(
      (const __attribute__((address_space(1))) unsigned int*)(uintptr_t)g,
      (__attribute__((address_space(3))) unsigned int*)(unsigned int)(uintptr_t)l,
      16, 0, 0);
}

__global__ void cvt_f32_bf16(const float* __restrict__ in,
                             unsigned short* __restrict__ out, int n4) {
  int i = blockIdx.x * blockDim.x + threadIdx.x;
  if (i < n4) {
    float4 f = ((const float4*)in)[i];
    ushort4 o;
    o.x = f2bf(f.x); o.y = f2bf(f.y); o.z = f2bf(f.z); o.w = f2bf(f.w);
    ((ushort4*)out)[i] = o;
  }
}

// mask int32 [B][S][S] -> bits [B][S][S/32]; column 0 forced true.
__global__ void pack_mask(const int* __restrict__ m, unsigned int* __restrict__ bits) {
  const int lane = threadIdx.x & 63;
  const size_t wid = ((size_t)blockIdx.x * blockDim.x + threadIdx.x) >> 6;
  const size_t base = wid * 256;  // 256 consecutive elements per wave
  unsigned long long bl[4];
#pragma unroll
  for (int c = 0; c < 4; ++c) {
    size_t e = base + (size_t)c * 64 + lane;
    int col = (int)(e & 4095);  // S = 4096
    bl[c] = __ballot((m[e] != 0) || (col == 0));
  }
  if (lane < 8)
    bits[base / 32 + lane] = (unsigned int)(bl[lane >> 1] >> ((lane & 1) * 32));
}

// C = A[M,K] @ B[N,K]^T (+ epilogue). Row-major, lda=K, ldb=K, ldc=N.
// EPI: 0 = +bias[n] store bf16 (K proj); 1 = +bias[m] store bf16 (V proj^T)
template <int EPI>
__global__ void __launch_bounds__(256)
gemm_bt(const unsigned short* __restrict__ A, const unsigned short* __restrict__ B,
        void* __restrict__ Cout, const float* __restrict__ bias,
        int M, int N, int K,
        long long strA, long long strB, long long strC) {
  __shared__ unsigned short sA[128 * 32];
  __shared__ unsigned short sB[128 * 32];

  const int tid  = threadIdx.x;
  const int lane = tid & 63;
  const int wave = tid >> 6;
  const int bz   = blockIdx.z;
  const int tn0  = blockIdx.x * 128;
  const int tm0  = blockIdx.y * 128;

  const unsigned short* Ab = A + (size_t)bz * strA;
  const unsigned short* Bb = B + (size_t)bz * strB;

  const int ldrow = lane >> 2;
  const int lcol  = (lane & 3) * 8;
  const int wm = (wave >> 1) * 64;
  const int wn = (wave & 1) * 64;
  const int lr = lane & 15;
  const int lq = lane >> 4;

  f32x4 acc[4][4] = {};

  for (int k0 = 0; k0 < K; k0 += 32) {
#pragma unroll
    for (int l = 0; l < 2; ++l) {
      const int row = wave * 32 + l * 16;
      async_load16(Ab + (size_t)(tm0 + row + ldrow) * K + (k0 + lcol), &sA[row * 32]);
      async_load16(Bb + (size_t)(tn0 + row + ldrow) * K + (k0 + lcol), &sB[row * 32]);
    }
    __syncthreads();

    bf16x8 af[4], bfr[4];
#pragma unroll
    for (int t = 0; t < 4; ++t) {
      af[t]  = *(const bf16x8*)&sA[(wm + t * 16 + lr) * 32 + lq * 8];
      bfr[t] = *(const bf16x8*)&sB[(wn + t * 16 + lr) * 32 + lq * 8];
    }
#pragma unroll
    for (int mt = 0; mt < 4; ++mt)
#pragma unroll
      for (int nt = 0; nt < 4; ++nt)
        acc[mt][nt] = __builtin_amdgcn_mfma_f32_16x16x32_bf16(af[mt], bfr[nt],
                                                              acc[mt][nt], 0, 0, 0);
    __syncthreads();
  }

#pragma unroll
  for (int mt = 0; mt < 4; ++mt)
#pragma unroll
    for (int nt = 0; nt < 4; ++nt)
#pragma unroll
      for (int r = 0; r < 4; ++r) {
        const int m = tm0 + wm + mt * 16 + lq * 4 + r;
        const int n = tn0 + wn + nt * 16 + lr;
        float v = acc[mt][nt][r];
        v += (EPI == 0) ? bias[n] : bias[m];
        ((unsigned short*)Cout)[(size_t)bz * strC + (size_t)m * N + n] = f2bf(v);
      }
}

// ---------------------------------------------------------------------------
// Fused: per block: batch b, 32 Q-rows. Loop 128-key k-tiles:
//   S(32x128) = Q(32x512) @ Kp_tile^T   (4 stages of BK=128, chunked BK=32)
//   sS = bf16(mask . relu(S))  via LDS round-trip (C-layout -> A-layout)
//   O(32x512) += sS @ Vp_tile           (Vpt B-frags direct from L2)
// 4 waves: wave w owns score n-slice [32w,32w+32) and PV e-slice [128w,128w+128)
// ---------------------------------------------------------------------------
__global__ void __launch_bounds__(256, 2)
fused_av(const unsigned short* __restrict__ Qb, const unsigned short* __restrict__ Kp,
         const unsigned short* __restrict__ Vpt, const unsigned int* __restrict__ mbits,
         float* __restrict__ out) {
  constexpr int S = 4096, E = 512;
  __shared__ unsigned short sQ[4 * 32 * 32];   // [kk][q][32k]   8 KB
  __shared__ unsigned short sK[4 * 128 * 32];  // [kk][krow][32k] 32 KB
  __shared__ unsigned short sS[4 * 32 * 32];   // [kk][q][32k]   8 KB

  const int tid = threadIdx.x;
  const int lane = tid & 63, w = tid >> 6;
  const int lr = lane & 15, lq = lane >> 4;
  const int b = blockIdx.y, q0 = blockIdx.x * 32;

  const unsigned short* Qrow = Qb + ((size_t)b * S + q0) * E;
  const unsigned short* Kpb  = Kp + (size_t)b * S * E;
  const unsigned short* Vptb = Vpt + (size_t)b * E * S;
  const unsigned int*   mb   = mbits + (size_t)b * S * (S / 32);

  f32x4 oacc[2][8] = {};

#pragma unroll 1
  for (int kt = 0; kt < S / 128; ++kt) {
    f32x4 sacc[2][2] = {};
#pragma unroll 1
    for (int stage = 0; stage < 4; ++stage) {
      __syncthreads();  // protect prior LDS reads before overwrite
      // stage Q chunk group (8 KB) + K chunk group (32 KB), m97 chunk layout
#pragma unroll
      for (int i = 0; i < 2; ++i) {
        int f = (tid + i * 256) * 16;
        int c = f >> 11, row = (f & 2047) >> 6, colb = f & 63;
        async_load16(Qrow + (size_t)row * E + (stage * 4 + c) * 32 + colb / 2,
                     (char*)sQ + f);
      }
#pragma unroll
      for (int i = 0; i < 8; ++i) {
        int f = (tid + i * 256) * 16;
        int kk = f >> 13, row = (f & 8191) >> 6, colb = f & 63;
        async_load16(Kpb + (size_t)(kt * 128 + row) * E + stage * 128 + kk * 32 + colb / 2,
                     (char*)sK + f);
      }
      __syncthreads();  // drain global_load_lds
#pragma unroll
      for (int kk = 0; kk < 4; ++kk) {
        bf16x8 aq[2], bk[2];
#pragma unroll
        for (int mt = 0; mt < 2; ++mt)
          aq[mt] = *(const bf16x8*)&sQ[(kk * 32 + mt * 16 + lr) * 32 + lq * 8];
#pragma unroll
        for (int nt = 0; nt < 2; ++nt)
          bk[nt] = *(const bf16x8*)&sK[(kk * 128 + w * 32 + nt * 16 + lr) * 32 + lq * 8];
#pragma unroll
        for (int mt = 0; mt < 2; ++mt)
#pragma unroll
          for (int nt = 0; nt < 2; ++nt)
            sacc[mt][nt] = __builtin_amdgcn_mfma_f32_16x16x32_bf16(
                aq[mt], bk[nt], sacc[mt][nt], 0, 0, 0);
      }
    }
    // mask + relu + bf16 -> sS (wave w writes chunk w; k_local = 32w+16nt+lr)
#pragma unroll
    for (int mt = 0; mt < 2; ++mt)
#pragma unroll
      for (int r = 0; r < 4; ++r) {
        const int q = mt * 16 + lq * 4 + r;
        const unsigned int word = mb[(size_t)(q0 + q) * (S / 32) + kt * 4 + w];
#pragma unroll
        for (int nt = 0; nt < 2; ++nt) {
          float v = sacc[mt][nt][r];
          v = ((word >> (nt * 16 + lr)) & 1u) ? fmaxf(v, 0.f) : 0.f;
          sS[(w * 32 + q) * 32 + nt * 16 + lr] = f2bf(v);
        }
      }
    __syncthreads();  // sS visible to all waves
    // PV: O += sS @ Vpt_tile ; B-frags 16B/lane direct from global (L2)
#pragma unroll
    for (int kk = 0; kk < 4; ++kk) {
      bf16x8 aS[2];
#pragma unroll
      for (int mt = 0; mt < 2; ++mt)
        aS[mt] = *(const bf16x8*)&sS[(kk * 32 + mt * 16 + lr) * 32 + lq * 8];
#pragma unroll
      for (int nt = 0; nt < 8; ++nt) {
        const bf16x8 bv = *(const bf16x8*)&Vptb[
            (size_t)(w * 128 + nt * 16 + lr) * S + kt * 128 + kk * 32 + lq * 8];
#pragma unroll
        for (int mt = 0; mt < 2; ++mt)
          oacc[mt][nt] = __builtin_amdgcn_mfma_f32_16x16x32_bf16(
              aS[mt], bv, oacc[mt][nt], 0, 0, 0);
      }
    }
  }
  // epilogue: fp32 out[b][q][e]
#pragma unroll
  for (int mt = 0; mt < 2; ++mt)
#pragma unroll
    for (int nt = 0; nt < 8; ++nt)
#pragma unroll
      for (int r = 0; r < 4; ++r)
        out[((size_t)b * S + q0 + mt * 16 + lq * 4 + r) * E + w * 128 + nt * 16 + lr] =
            oacc[mt][nt][r];
}

extern "C" void kernel_launch(void* const* d_in, const int* in_sizes, int n_in,
                              void* d_out, int out_size, void* d_ws, size_t ws_size,
                              hipStream_t stream) {
  const float* query = (const float*)d_in[0];
  const float* key   = (const float*)d_in[1];
  const float* value = (const float*)d_in[2];
  const int*   mask  = (const int*)d_in[3];
  const float* W1    = (const float*)d_in[4];
  const float* b1    = (const float*)d_in[5];
  const float* W2    = (const float*)d_in[6];
  const float* b2    = (const float*)d_in[7];
  float* out = (float*)d_out;

  constexpr int B = 4, S = 4096, E = 512;
  constexpr long long BSE = (long long)B * S * E;
  constexpr long long SE  = (long long)S * E;
  constexpr long long BSS = (long long)B * S * S;
  constexpr long long EE  = (long long)E * E;

  char* ws = (char*)d_ws;
  unsigned short* Qb   = (unsigned short*)ws;  ws += BSE * 2;
  unsigned short* Kb   = (unsigned short*)ws;  ws += BSE * 2;
  unsigned short* Vb   = (unsigned short*)ws;  ws += BSE * 2;
  unsigned short* W1b  = (unsigned short*)ws;  ws += EE * 2;
  unsigned short* W2b  = (unsigned short*)ws;  ws += EE * 2;
  unsigned short* Kp   = (unsigned short*)ws;  ws += BSE * 2;  // [B*S, E]
  unsigned short* Vpt  = (unsigned short*)ws;  ws += BSE * 2;  // [B][E][S]
  unsigned int*   mbit = (unsigned int*)ws;    ws += BSS / 8;  // [B][S][S/32]

  cvt_f32_bf16<<<dim3(BSE / 1024), 256, 0, stream>>>(query, Qb, (int)(BSE / 4));
  cvt_f32_bf16<<<dim3(BSE / 1024), 256, 0, stream>>>(key,   Kb, (int)(BSE / 4));
  cvt_f32_bf16<<<dim3(BSE / 1024), 256, 0, stream>>>(value, Vb, (int)(BSE / 4));
  cvt_f32_bf16<<<dim3(EE / 1024),  256, 0, stream>>>(W1, W1b, (int)(EE / 4));
  cvt_f32_bf16<<<dim3(EE / 1024),  256, 0, stream>>>(W2, W2b, (int)(EE / 4));

  pack_mask<<<dim3((int)(BSS / 1024)), 256, 0, stream>>>(mask, mbit);

  // Kp = Kb @ W1^T + b1
  gemm_bt<0><<<dim3(E / 128, (B * S) / 128, 1), 256, 0, stream>>>(
      Kb, W1b, Kp, b1, B * S, E, E, 0, 0, 0);
  // Vpt[b][f][s] = W2 @ Vb^T + b2
  gemm_bt<1><<<dim3(S / 128, E / 128, B), 256, 0, stream>>>(
      W2b, Vb, Vpt, b2, E, S, E, 0, SE, SE);

  // fused masked-relu attention
  fused_av<<<dim3(S / 32, B), 256, 0, stream>>>(Qb, Kp, Vpt, mbit, out);
}

// Round 3
// 729.226 us; speedup vs baseline: 1.3067x; 1.3067x over previous
//
#include <hip/hip_runtime.h>
#include <cstdint>

// ---------------------------------------------------------------------------
// PureCorrelation: out = (mask' . relu(Q @ Kp^T)) @ Vp
//   Kp = K W1^T + b1,  Vp = V W2^T + b2,  mask' = mask with col0 true.
// R3: unfused m97-structure GEMMs (R1) + bit-packed mask (R2) applied in the
// alpha GEMM epilogue as one 8B broadcast load per 16 outputs, replacing
// 268 MB of scalar int32 mask reads with 8.4 MB of bits.
// ---------------------------------------------------------------------------

typedef __bf16 bf16x8 __attribute__((ext_vector_type(8)));
typedef float f32x4 __attribute__((ext_vector_type(4)));

__device__ __forceinline__ unsigned short f2bf(float f) {
  unsigned int u = __float_as_uint(f);
  u += 0x7fffu + ((u >> 16) & 1u);
  return (unsigned short)(u >> 16);
}

// async global->LDS, 16B per lane. LDS dest is wave-uniform base + lane*16.
__device__ __forceinline__ void async_load16(const void* g, void* l) {
  __builtin_amdgcn_global_load_lds(
      (const __attribute__((address_space(1))) unsigned int*)(uintptr_t)g,
      (__attribute__((address_space(3))) unsigned int*)(unsigned int)(uintptr_t)l,
      16, 0, 0);
}

__global__ void cvt_f32_bf16(const float* __restrict__ in,
                             unsigned short* __restrict__ out, int n4) {
  int i = blockIdx.x * blockDim.x + threadIdx.x;
  if (i < n4) {
    float4 f = ((const float4*)in)[i];
    ushort4 o;
    o.x = f2bf(f.x); o.y = f2bf(f.y); o.z = f2bf(f.z); o.w = f2bf(f.w);
    ((ushort4*)out)[i] = o;
  }
}

// mask int32 [B][S][S] -> bits [B][S][S/32]; column 0 forced true.
__global__ void pack_mask(const int* __restrict__ m, unsigned int* __restrict__ bits) {
  const int lane = threadIdx.x & 63;
  const size_t wid = ((size_t)blockIdx.x * blockDim.x + threadIdx.x) >> 6;
  const size_t base = wid * 256;  // 256 consecutive elements per wave
  unsigned long long bl[4];
#pragma unroll
  for (int c = 0; c < 4; ++c) {
    size_t e = base + (size_t)c * 64 + lane;
    int col = (int)(e & 4095);  // S = 4096
    bl[c] = __ballot((m[e] != 0) || (col == 0));
  }
  if (lane < 8)
    bits[base / 32 + lane] = (unsigned int)(bl[lane >> 1] >> ((lane & 1) * 32));
}

// C = A[M,K] @ B[N,K]^T (+ epilogue). Row-major, lda=K, ldb=K, ldc=N.
// EPI: 0 = +bias[n] store bf16 (K proj)
//      1 = +bias[m] store bf16 (V proj, transposed output)
//      2 = bitmask+relu store bf16 (alpha)
//      3 = plain store fp32 (final out)
template <int EPI>
__global__ void __launch_bounds__(256)
gemm_bt(const unsigned short* __restrict__ A, const unsigned short* __restrict__ B,
        void* __restrict__ Cout, const float* __restrict__ bias,
        const unsigned int* __restrict__ mbits,
        int M, int N, int K,
        long long strA, long long strB, long long strC, long long strM) {
  __shared__ unsigned short sA[128 * 32];
  __shared__ unsigned short sB[128 * 32];

  const int tid  = threadIdx.x;
  const int lane = tid & 63;
  const int wave = tid >> 6;
  const int bz   = blockIdx.z;
  const int tn0  = blockIdx.x * 128;
  const int tm0  = blockIdx.y * 128;

  const unsigned short* Ab = A + (size_t)bz * strA;
  const unsigned short* Bb = B + (size_t)bz * strB;

  const int ldrow = lane >> 2;        // row within a 16-row wave-load
  const int lcol  = (lane & 3) * 8;   // k-element offset within BK=32
  const int wm = (wave >> 1) * 64;
  const int wn = (wave & 1) * 64;
  const int lr = lane & 15;
  const int lq = lane >> 4;

  f32x4 acc[4][4] = {};

  for (int k0 = 0; k0 < K; k0 += 32) {
#pragma unroll
    for (int l = 0; l < 2; ++l) {
      const int row = wave * 32 + l * 16;
      async_load16(Ab + (size_t)(tm0 + row + ldrow) * K + (k0 + lcol), &sA[row * 32]);
      async_load16(Bb + (size_t)(tn0 + row + ldrow) * K + (k0 + lcol), &sB[row * 32]);
    }
    __syncthreads();

    bf16x8 af[4], bfr[4];
#pragma unroll
    for (int t = 0; t < 4; ++t) {
      af[t]  = *(const bf16x8*)&sA[(wm + t * 16 + lr) * 32 + lq * 8];
      bfr[t] = *(const bf16x8*)&sB[(wn + t * 16 + lr) * 32 + lq * 8];
    }
#pragma unroll
    for (int mt = 0; mt < 4; ++mt)
#pragma unroll
      for (int nt = 0; nt < 4; ++nt)
        acc[mt][nt] = __builtin_amdgcn_mfma_f32_16x16x32_bf16(af[mt], bfr[nt],
                                                              acc[mt][nt], 0, 0, 0);
    __syncthreads();
  }

  // epilogue: C/D layout col = lane&15, row = (lane>>4)*4 + reg
#pragma unroll
  for (int mt = 0; mt < 4; ++mt) {
#pragma unroll
    for (int r = 0; r < 4; ++r) {
      const int m = tm0 + wm + mt * 16 + lq * 4 + r;
      unsigned long long w64 = 0;
      if constexpr (EPI == 2) {
        // one aligned 8B word covers this thread's 64-wide n-window
        w64 = *(const unsigned long long*)&mbits[(size_t)bz * strM +
                                                 (size_t)m * (N >> 5) + ((tn0 + wn) >> 5)];
      }
#pragma unroll
      for (int nt = 0; nt < 4; ++nt) {
        const int n = tn0 + wn + nt * 16 + lr;
        float v = acc[mt][nt][r];
        if constexpr (EPI == 0) {
          v += bias[n];
          ((unsigned short*)Cout)[(size_t)bz * strC + (size_t)m * N + n] = f2bf(v);
        } else if constexpr (EPI == 1) {
          v += bias[m];
          ((unsigned short*)Cout)[(size_t)bz * strC + (size_t)m * N + n] = f2bf(v);
        } else if constexpr (EPI == 2) {
          v = ((w64 >> (nt * 16 + lr)) & 1ull) ? fmaxf(v, 0.f) : 0.f;
          ((unsigned short*)Cout)[(size_t)bz * strC + (size_t)m * N + n] = f2bf(v);
        } else {
          ((float*)Cout)[(size_t)bz * strC + (size_t)m * N + n] = v;
        }
      }
    }
  }
}

extern "C" void kernel_launch(void* const* d_in, const int* in_sizes, int n_in,
                              void* d_out, int out_size, void* d_ws, size_t ws_size,
                              hipStream_t stream) {
  const float* query = (const float*)d_in[0];
  const float* key   = (const float*)d_in[1];
  const float* value = (const float*)d_in[2];
  const int*   mask  = (const int*)d_in[3];
  const float* W1    = (const float*)d_in[4];
  const float* b1    = (const float*)d_in[5];
  const float* W2    = (const float*)d_in[6];
  const float* b2    = (const float*)d_in[7];
  float* out = (float*)d_out;

  constexpr int B = 4, S = 4096, E = 512;
  constexpr long long BSE = (long long)B * S * E;
  constexpr long long SE  = (long long)S * E;
  constexpr long long SS  = (long long)S * S;
  constexpr long long BSS = (long long)B * S * S;
  constexpr long long EE  = (long long)E * E;

  char* ws = (char*)d_ws;
  unsigned short* Qb   = (unsigned short*)ws;  ws += BSE * 2;
  unsigned short* Kb   = (unsigned short*)ws;  ws += BSE * 2;
  unsigned short* Vb   = (unsigned short*)ws;  ws += BSE * 2;
  unsigned short* W1b  = (unsigned short*)ws;  ws += EE * 2;
  unsigned short* W2b  = (unsigned short*)ws;  ws += EE * 2;
  unsigned short* Kp   = (unsigned short*)ws;  ws += BSE * 2;   // [B*S, E]
  unsigned short* Vpt  = (unsigned short*)ws;  ws += BSE * 2;   // [B][E][S]
  unsigned short* alph = (unsigned short*)ws;  ws += BSS * 2;   // [B][S][S]
  unsigned int*   mbit = (unsigned int*)ws;    ws += BSS / 8;   // [B][S][S/32]

  // fp32 -> bf16 casts
  cvt_f32_bf16<<<dim3(BSE / 1024), 256, 0, stream>>>(query, Qb, (int)(BSE / 4));
  cvt_f32_bf16<<<dim3(BSE / 1024), 256, 0, stream>>>(key,   Kb, (int)(BSE / 4));
  cvt_f32_bf16<<<dim3(BSE / 1024), 256, 0, stream>>>(value, Vb, (int)(BSE / 4));
  cvt_f32_bf16<<<dim3(EE / 1024),  256, 0, stream>>>(W1, W1b, (int)(EE / 4));
  cvt_f32_bf16<<<dim3(EE / 1024),  256, 0, stream>>>(W2, W2b, (int)(EE / 4));

  // int32 mask -> bits (col 0 forced true)
  pack_mask<<<dim3((int)(BSS / 1024)), 256, 0, stream>>>(mask, mbit);

  // Kp = Kb @ W1^T + b1   (M=B*S, N=E, K=E)
  gemm_bt<0><<<dim3(E / 128, (B * S) / 128, 1), 256, 0, stream>>>(
      Kb, W1b, Kp, b1, nullptr, B * S, E, E, 0, 0, 0, 0);

  // Vpt[b][f][s] = W2 @ Vb^T + b2   (M=E, N=S, K=E, per batch)
  gemm_bt<1><<<dim3(S / 128, E / 128, B), 256, 0, stream>>>(
      W2b, Vb, Vpt, b2, nullptr, E, S, E, 0, SE, SE, 0);

  // alpha = bitmask-relu(Qb @ Kp^T)   (M=N=S, K=E, per batch)
  gemm_bt<2><<<dim3(S / 128, S / 128, B), 256, 0, stream>>>(
      Qb, Kp, alph, nullptr, mbit, S, S, E, SE, SE, SS, SS / 32);

  // out = alpha @ Vpt^T   (M=S, N=E, K=S, per batch)
  gemm_bt<3><<<dim3(E / 128, S / 128, B), 256, 0, stream>>>(
      alph, Vpt, out, nullptr, nullptr, S, E, S, SS, SE, SE, 0);
}